// Round 1
// baseline (1677.585 us; speedup 1.0000x reference)
//
#include <hip/hip_runtime.h>
#include <math.h>

// Problem constants (from reference)
constexpr int N_EDGES = 800000;
constexpr int D_COORD = 16;
constexpr int N_FEAT  = 8;
constexpr int D_IN    = 40;   // 8 + 16 + 16
constexpr int H       = 64;
constexpr int D_OUT   = 16;

// One thread = one edge. Computes one MLP (40->64->64->16) in registers and
// scatter-adds the masked output to acc[node]. Weights are wave-uniform:
// accessed with uniform indices through __restrict__ const pointers so the
// backend can scalarize them to s_load + v_fmac-with-SGPR.
__global__ __launch_bounds__(256) void edge_mlp(
    const float* __restrict__ coords,
    const float* __restrict__ feat,
    const float* __restrict__ mask,
    const int*   __restrict__ a_from,
    const int*   __restrict__ a_to,
    const float* __restrict__ W0, const float* __restrict__ b0,
    const float* __restrict__ W1, const float* __restrict__ b1,
    const float* __restrict__ W2, const float* __restrict__ b2,
    float* __restrict__ acc,
    const int use_to)
{
    const int e = blockIdx.x * blockDim.x + threadIdx.x;
    if (e >= N_EDGES) return;

    const float m  = mask[e];
    const int   nf = a_from[e];
    const int   nt = a_to[e];

    // ---- build masked input x[40] = m * [feat(8) | coords[from](16) | coords[to](16)]
    float x[D_IN];
    {
        const float4* f4 = reinterpret_cast<const float4*>(feat + (size_t)e * N_FEAT);
        float4 v0 = f4[0];
        float4 v1 = f4[1];
        x[0]=v0.x; x[1]=v0.y; x[2]=v0.z; x[3]=v0.w;
        x[4]=v1.x; x[5]=v1.y; x[6]=v1.z; x[7]=v1.w;
        const float4* cf = reinterpret_cast<const float4*>(coords + (size_t)nf * D_COORD);
        #pragma unroll
        for (int i = 0; i < 4; ++i) {
            float4 v = cf[i];
            x[8 + 4*i + 0] = v.x; x[8 + 4*i + 1] = v.y;
            x[8 + 4*i + 2] = v.z; x[8 + 4*i + 3] = v.w;
        }
        const float4* ct = reinterpret_cast<const float4*>(coords + (size_t)nt * D_COORD);
        #pragma unroll
        for (int i = 0; i < 4; ++i) {
            float4 v = ct[i];
            x[24 + 4*i + 0] = v.x; x[24 + 4*i + 1] = v.y;
            x[24 + 4*i + 2] = v.z; x[24 + 4*i + 3] = v.w;
        }
    }
    #pragma unroll
    for (int i = 0; i < D_IN; ++i) x[i] *= m;

    // ---- layer 1: 40 -> 64, ReLU
    float h0[H];
    #pragma unroll
    for (int j = 0; j < H; ++j) h0[j] = b0[j];
    #pragma unroll
    for (int i = 0; i < D_IN; ++i) {
        const float xi = x[i];
        const float* __restrict__ w = W0 + i * H;
        #pragma unroll
        for (int j = 0; j < H; ++j) h0[j] = fmaf(xi, w[j], h0[j]);
    }
    #pragma unroll
    for (int j = 0; j < H; ++j) h0[j] = fmaxf(h0[j], 0.0f);

    // ---- layer 2: 64 -> 64, ReLU
    float h1[H];
    #pragma unroll
    for (int j = 0; j < H; ++j) h1[j] = b1[j];
    #pragma unroll
    for (int i = 0; i < H; ++i) {
        const float hi = h0[i];
        const float* __restrict__ w = W1 + i * H;
        #pragma unroll
        for (int j = 0; j < H; ++j) h1[j] = fmaf(hi, w[j], h1[j]);
    }
    #pragma unroll
    for (int j = 0; j < H; ++j) h1[j] = fmaxf(h1[j], 0.0f);

    // ---- layer 3: 64 -> 16 (no activation)
    float o[D_OUT];
    #pragma unroll
    for (int j = 0; j < D_OUT; ++j) o[j] = b2[j];
    #pragma unroll
    for (int i = 0; i < H; ++i) {
        const float hi = h1[i];
        const float* __restrict__ w = W2 + i * D_OUT;
        #pragma unroll
        for (int j = 0; j < D_OUT; ++j) o[j] = fmaf(hi, w[j], o[j]);
    }

    // ---- masked scatter-add
    const int node = use_to ? nt : nf;
    float* __restrict__ dst = acc + (size_t)node * D_OUT;
    #pragma unroll
    for (int j = 0; j < D_OUT; ++j) {
        atomicAdd(dst + j, o[j] * m);
    }
}

__global__ __launch_bounds__(256) void tanh_inplace(float* __restrict__ p, int n4)
{
    const int i = blockIdx.x * blockDim.x + threadIdx.x;
    if (i >= n4) return;
    float4 v = reinterpret_cast<float4*>(p)[i];
    v.x = tanhf(v.x); v.y = tanhf(v.y); v.z = tanhf(v.z); v.w = tanhf(v.w);
    reinterpret_cast<float4*>(p)[i] = v;
}

extern "C" void kernel_launch(void* const* d_in, const int* in_sizes, int n_in,
                              void* d_out, int out_size, void* d_ws, size_t ws_size,
                              hipStream_t stream)
{
    const float* coords = (const float*)d_in[0];
    const float* feat   = (const float*)d_in[1];
    const float* mask   = (const float*)d_in[2];
    const int*   a_from = (const int*)d_in[3];
    const int*   a_to   = (const int*)d_in[4];
    const float* fW0 = (const float*)d_in[5];
    const float* fb0 = (const float*)d_in[6];
    const float* fW1 = (const float*)d_in[7];
    const float* fb1 = (const float*)d_in[8];
    const float* fW2 = (const float*)d_in[9];
    const float* fb2 = (const float*)d_in[10];
    const float* tW0 = (const float*)d_in[11];
    const float* tb0 = (const float*)d_in[12];
    const float* tW1 = (const float*)d_in[13];
    const float* tb1 = (const float*)d_in[14];
    const float* tW2 = (const float*)d_in[15];
    const float* tb2 = (const float*)d_in[16];

    float* out = (float*)d_out;

    // acc starts at zero (d_out is poisoned 0xAA before every timed launch)
    hipMemsetAsync(out, 0, (size_t)out_size * sizeof(float), stream);

    const dim3 blk(256);
    const dim3 grd((N_EDGES + 255) / 256);
    edge_mlp<<<grd, blk, 0, stream>>>(coords, feat, mask, a_from, a_to,
                                      fW0, fb0, fW1, fb1, fW2, fb2, out, 0);
    edge_mlp<<<grd, blk, 0, stream>>>(coords, feat, mask, a_from, a_to,
                                      tW0, tb0, tW1, tb1, tW2, tb2, out, 1);

    const int n4 = out_size / 4;  // out_size = 100000*16, divisible by 4
    tanh_inplace<<<(n4 + 255) / 256, 256, 0, stream>>>(out, n4);
}

// Round 2
// 472.854 us; speedup vs baseline: 3.5478x; 3.5478x over previous
//
#include <hip/hip_runtime.h>
#include <math.h>

constexpr int N_EDGES = 800000;
constexpr int D_COORD = 16;
constexpr int N_FEAT  = 8;
constexpr int D_IN    = 40;   // 8 + 16 + 16
constexpr int H       = 64;
constexpr int D_OUT   = 16;
constexpr int ET      = 64;   // edges per block (800000 % 64 == 0)
constexpr int XP      = 68;   // padded LDS row stride (floats): 4*68 % 32 == 16
                              // -> staging writes 2-way, compute reads conflict-free,
                              // H-writes at the b128 bandwidth floor

// Fused edge-MLP: per block, stage 64 edges' inputs once, run both MLPs
// (f and t) as three tiled GEMMs each, scatter-add masked outputs.
// Thread layout for L1/L2: tx=tid&15 owns 4 outputs, ty=tid>>4 owns 4 edges.
__global__ __launch_bounds__(256) void edge_mlp_tiled(
    const float* __restrict__ coords,
    const float* __restrict__ feat,
    const float* __restrict__ mask,
    const int*   __restrict__ a_from,
    const int*   __restrict__ a_to,
    const float* __restrict__ fW0, const float* __restrict__ fb0,
    const float* __restrict__ fW1, const float* __restrict__ fb1,
    const float* __restrict__ fW2, const float* __restrict__ fb2,
    const float* __restrict__ tW0, const float* __restrict__ tb0,
    const float* __restrict__ tW1, const float* __restrict__ tb1,
    const float* __restrict__ tW2, const float* __restrict__ tb2,
    float* __restrict__ acc_out)
{
    __shared__ float Xs[D_IN * XP];   // X^T: Xs[k][e], masked input
    __shared__ float Ws[H * H];       // current layer's weights (row-major KxN)
    __shared__ float Hs[H * XP];      // H^T: Hs[j][e]
    __shared__ float ms[ET];
    __shared__ int   nodes[2][ET];

    const int tid = threadIdx.x;
    const int e0  = blockIdx.x * ET;

    // ---------------- staging: mask, node ids, X^T = m * [feat | c_from | c_to]
    if (tid < ET) {
        ms[tid]       = mask[e0 + tid];
        nodes[0][tid] = a_from[e0 + tid];
        nodes[1][tid] = a_to[e0 + tid];
    }
    if (tid < 128) {                       // feat: rows 0..7
        const int e = tid >> 1, half = tid & 1;
        const float m = mask[e0 + e];
        float4 v = reinterpret_cast<const float4*>(feat)[(size_t)(e0 + e) * 2 + half];
        const int r = half * 4;
        Xs[(r + 0) * XP + e] = v.x * m;
        Xs[(r + 1) * XP + e] = v.y * m;
        Xs[(r + 2) * XP + e] = v.z * m;
        Xs[(r + 3) * XP + e] = v.w * m;
    }
    {                                      // coords: rows 8..23 (from), 24..39 (to)
        const int e = tid >> 2, q = tid & 3;
        const float m = mask[e0 + e];
        const int nf = a_from[e0 + e];
        const int nt = a_to[e0 + e];
        float4 cf = reinterpret_cast<const float4*>(coords)[(size_t)nf * 4 + q];
        float4 ct = reinterpret_cast<const float4*>(coords)[(size_t)nt * 4 + q];
        const int rf = 8 + q * 4, rt = 24 + q * 4;
        Xs[(rf + 0) * XP + e] = cf.x * m;
        Xs[(rf + 1) * XP + e] = cf.y * m;
        Xs[(rf + 2) * XP + e] = cf.z * m;
        Xs[(rf + 3) * XP + e] = cf.w * m;
        Xs[(rt + 0) * XP + e] = ct.x * m;
        Xs[(rt + 1) * XP + e] = ct.y * m;
        Xs[(rt + 2) * XP + e] = ct.z * m;
        Xs[(rt + 3) * XP + e] = ct.w * m;
    }

    const int tx = tid & 15, ty = tid >> 4;

    auto run_mlp = [&](const float* __restrict__ W0, const float* __restrict__ b0,
                       const float* __restrict__ W1, const float* __restrict__ b1,
                       const float* __restrict__ W2, const float* __restrict__ b2,
                       const int which)
    {
        float a[4][4];

        // ---- load W0 (previous phase's Ws reads are fenced by the barrier)
        __syncthreads();
        {
            const float4* s4 = reinterpret_cast<const float4*>(W0);
            float4* d4 = reinterpret_cast<float4*>(Ws);
            #pragma unroll
            for (int i = 0; i < (D_IN * H / 4 + 255) / 256; ++i) {
                int idx = tid + i * 256;
                if (idx < D_IN * H / 4) d4[idx] = s4[idx];
            }
        }
        __syncthreads();

        // ---- layer 1: 40 -> 64, ReLU  (reads Xs, Ws)
        {
            float4 bv = reinterpret_cast<const float4*>(b0)[tx];
            #pragma unroll
            for (int i = 0; i < 4; ++i) {
                a[i][0] = bv.x; a[i][1] = bv.y; a[i][2] = bv.z; a[i][3] = bv.w;
            }
            #pragma unroll 8
            for (int k = 0; k < D_IN; ++k) {
                float4 xv = *reinterpret_cast<const float4*>(&Xs[k * XP + ty * 4]);
                float4 wv = *reinterpret_cast<const float4*>(&Ws[k * H + tx * 4]);
                const float xc[4] = {xv.x, xv.y, xv.z, xv.w};
                const float wc[4] = {wv.x, wv.y, wv.z, wv.w};
                #pragma unroll
                for (int i = 0; i < 4; ++i)
                    #pragma unroll
                    for (int j = 0; j < 4; ++j)
                        a[i][j] = fmaf(xc[i], wc[j], a[i][j]);
            }
            #pragma unroll
            for (int i = 0; i < 4; ++i)
                #pragma unroll
                for (int j = 0; j < 4; ++j)
                    a[i][j] = fmaxf(a[i][j], 0.0f);
        }
        __syncthreads();

        // ---- write H0^T, load W1
        #pragma unroll
        for (int j = 0; j < 4; ++j) {
            const int r = tx * 4 + j;
            float4 hv = make_float4(a[0][j], a[1][j], a[2][j], a[3][j]);
            *reinterpret_cast<float4*>(&Hs[r * XP + ty * 4]) = hv;
        }
        {
            const float4* s4 = reinterpret_cast<const float4*>(W1);
            float4* d4 = reinterpret_cast<float4*>(Ws);
            #pragma unroll
            for (int i = 0; i < H * H / 4 / 256; ++i)
                d4[tid + i * 256] = s4[tid + i * 256];
        }
        __syncthreads();

        // ---- layer 2: 64 -> 64, ReLU  (reads Hs, Ws)
        {
            float4 bv = reinterpret_cast<const float4*>(b1)[tx];
            float acc2[4][4];
            #pragma unroll
            for (int i = 0; i < 4; ++i) {
                acc2[i][0] = bv.x; acc2[i][1] = bv.y; acc2[i][2] = bv.z; acc2[i][3] = bv.w;
            }
            #pragma unroll 8
            for (int k = 0; k < H; ++k) {
                float4 xv = *reinterpret_cast<const float4*>(&Hs[k * XP + ty * 4]);
                float4 wv = *reinterpret_cast<const float4*>(&Ws[k * H + tx * 4]);
                const float xc[4] = {xv.x, xv.y, xv.z, xv.w};
                const float wc[4] = {wv.x, wv.y, wv.z, wv.w};
                #pragma unroll
                for (int i = 0; i < 4; ++i)
                    #pragma unroll
                    for (int j = 0; j < 4; ++j)
                        acc2[i][j] = fmaf(xc[i], wc[j], acc2[i][j]);
            }
            #pragma unroll
            for (int i = 0; i < 4; ++i)
                #pragma unroll
                for (int j = 0; j < 4; ++j)
                    a[i][j] = fmaxf(acc2[i][j], 0.0f);
        }
        __syncthreads();

        // ---- write H1^T (overwrite Hs — all reads fenced), load W2
        #pragma unroll
        for (int j = 0; j < 4; ++j) {
            const int r = tx * 4 + j;
            float4 hv = make_float4(a[0][j], a[1][j], a[2][j], a[3][j]);
            *reinterpret_cast<float4*>(&Hs[r * XP + ty * 4]) = hv;
        }
        {
            const float4* s4 = reinterpret_cast<const float4*>(W2);
            float4* d4 = reinterpret_cast<float4*>(Ws);
            if (tid < H * D_OUT / 4) d4[tid] = s4[tid];
        }
        __syncthreads();

        // ---- layer 3: 64 -> 16  (reads Hs, Ws); epilogue: masked atomic scatter
        {
            const int ox = tid & 15, ey = tid >> 4;   // 16 outputs x (16x4) edges
            float o[4];
            const float bo = b2[ox];
            #pragma unroll
            for (int i = 0; i < 4; ++i) o[i] = bo;
            #pragma unroll 8
            for (int k = 0; k < H; ++k) {
                float4 xv = *reinterpret_cast<const float4*>(&Hs[k * XP + ey * 4]);
                const float wv = Ws[k * D_OUT + ox];
                o[0] = fmaf(xv.x, wv, o[0]);
                o[1] = fmaf(xv.y, wv, o[1]);
                o[2] = fmaf(xv.z, wv, o[2]);
                o[3] = fmaf(xv.w, wv, o[3]);
            }
            #pragma unroll
            for (int i = 0; i < 4; ++i) {
                const int e = ey * 4 + i;
                const float m = ms[e];
                const int node = nodes[which][e];
                atomicAdd(acc_out + (size_t)node * D_OUT + ox, o[i] * m);
            }
        }
    };

    run_mlp(fW0, fb0, fW1, fb1, fW2, fb2, 0);
    run_mlp(tW0, tb0, tW1, tb1, tW2, tb2, 1);
}

__global__ __launch_bounds__(256) void tanh_inplace(float* __restrict__ p, int n4)
{
    const int i = blockIdx.x * blockDim.x + threadIdx.x;
    if (i >= n4) return;
    float4 v = reinterpret_cast<float4*>(p)[i];
    v.x = tanhf(v.x); v.y = tanhf(v.y); v.z = tanhf(v.z); v.w = tanhf(v.w);
    reinterpret_cast<float4*>(p)[i] = v;
}

extern "C" void kernel_launch(void* const* d_in, const int* in_sizes, int n_in,
                              void* d_out, int out_size, void* d_ws, size_t ws_size,
                              hipStream_t stream)
{
    const float* coords = (const float*)d_in[0];
    const float* feat   = (const float*)d_in[1];
    const float* mask   = (const float*)d_in[2];
    const int*   a_from = (const int*)d_in[3];
    const int*   a_to   = (const int*)d_in[4];
    const float* fW0 = (const float*)d_in[5];
    const float* fb0 = (const float*)d_in[6];
    const float* fW1 = (const float*)d_in[7];
    const float* fb1 = (const float*)d_in[8];
    const float* fW2 = (const float*)d_in[9];
    const float* fb2 = (const float*)d_in[10];
    const float* tW0 = (const float*)d_in[11];
    const float* tb0 = (const float*)d_in[12];
    const float* tW1 = (const float*)d_in[13];
    const float* tb1 = (const float*)d_in[14];
    const float* tW2 = (const float*)d_in[15];
    const float* tb2 = (const float*)d_in[16];

    float* out = (float*)d_out;

    hipMemsetAsync(out, 0, (size_t)out_size * sizeof(float), stream);

    edge_mlp_tiled<<<N_EDGES / ET, 256, 0, stream>>>(
        coords, feat, mask, a_from, a_to,
        fW0, fb0, fW1, fb1, fW2, fb2,
        tW0, tb0, tW1, tb1, tW2, tb2, out);

    const int n4 = out_size / 4;
    tanh_inplace<<<(n4 + 255) / 256, 256, 0, stream>>>(out, n4);
}